// Round 1
// baseline (100.817 us; speedup 1.0000x reference)
//
#include <hip/hip_runtime.h>

// QuantumKernelMethod: analytic collapse.
// The circuit = (permutation ∘ diagonal-phase)^4 applied to a REAL product
// state. Phases/permutation depend only on params (shared by X and Y states),
// so they cancel in <psi_x|psi_y>:
//   M[x,y] = prod_i cos((x_i - y_i)/2),   out = M^2.
// params is unused. Store-BW-bound: 64 MB fp32 output.

#define NS 4096   // samples per set
#define NW 10     // wires

__global__ __launch_bounds__(256) void qkm_precompute(
    const float* __restrict__ X, const float* __restrict__ Y,
    float2* __restrict__ csx, float2* __restrict__ csy) {
    int tid = blockIdx.x * 256 + threadIdx.x;      // 0 .. 2*NW*NS-1 (81920)
    int set = tid / (NW * NS);
    int rem = tid - set * (NW * NS);
    int w = rem >> 12;                              // wire (rem / 4096)
    int sample = rem & (NS - 1);
    const float* src = set ? Y : X;
    float2* dst = set ? csy : csx;
    float a = 0.5f * src[sample * NW + w];
    float s, c;
    sincosf(a, &s, &c);
    dst[w * NS + sample] = make_float2(c, s);       // wire-major: coalesced cols
}

__global__ __launch_bounds__(256) void qkm_gram(
    const float2* __restrict__ csx, const float2* __restrict__ csy,
    float* __restrict__ out) {
    const int col = (blockIdx.x * 256 + threadIdx.x) * 4;  // 4 cols per thread
    const int row0 = blockIdx.y * 8;                       // 8 rows per block

    // Load this thread's 4 columns' (cos,sin) for all 10 wires: 2 float4s/wire.
    float yc[NW][4], ys[NW][4];
#pragma unroll
    for (int w = 0; w < NW; ++w) {
        const float4* p = reinterpret_cast<const float4*>(csy + w * NS + col);
        float4 a = p[0];
        float4 b = p[1];
        yc[w][0] = a.x; ys[w][0] = a.y;
        yc[w][1] = a.z; ys[w][1] = a.w;
        yc[w][2] = b.x; ys[w][2] = b.y;
        yc[w][3] = b.z; ys[w][3] = b.w;
    }

#pragma unroll 2
    for (int r = 0; r < 8; ++r) {
        const int row = row0 + r;                   // uniform across the wave
        float p0 = 1.f, p1 = 1.f, p2 = 1.f, p3 = 1.f;
#pragma unroll
        for (int w = 0; w < NW; ++w) {
            const float2 xc = csx[w * NS + row];    // uniform -> scalar load
            p0 *= fmaf(xc.y, ys[w][0], xc.x * yc[w][0]);
            p1 *= fmaf(xc.y, ys[w][1], xc.x * yc[w][1]);
            p2 *= fmaf(xc.y, ys[w][2], xc.x * yc[w][2]);
            p3 *= fmaf(xc.y, ys[w][3], xc.x * yc[w][3]);
        }
        float4 o;
        o.x = p0 * p0; o.y = p1 * p1; o.z = p2 * p2; o.w = p3 * p3;
        *reinterpret_cast<float4*>(out + (size_t)row * NS + col) = o;
    }
}

extern "C" void kernel_launch(void* const* d_in, const int* in_sizes, int n_in,
                              void* d_out, int out_size, void* d_ws, size_t ws_size,
                              hipStream_t stream) {
    const float* X = (const float*)d_in[0];   // (4096, 10)
    const float* Y = (const float*)d_in[1];   // (4096, 10)
    // d_in[2] = params (4,10): provably unused (phases cancel in |<x|y>|^2).
    float* out = (float*)d_out;               // (4096, 4096) fp32

    float2* csx = (float2*)d_ws;              // [NW][NS] (cos,sin) for X
    float2* csy = csx + NW * NS;              // [NW][NS] (cos,sin) for Y

    qkm_precompute<<<(2 * NW * NS) / 256, 256, 0, stream>>>(X, Y, csx, csy);

    dim3 grid(NS / (256 * 4), NS / 8);        // (4, 512)
    qkm_gram<<<grid, 256, 0, stream>>>(csx, csy, out);
}